// Round 3
// baseline (272.245 us; speedup 1.0000x reference)
//
#include <hip/hip_runtime.h>
#include <hip/hip_bf16.h>
#include <math.h>

// Problem constants
#define Bz 8
#define Lz 2048
#define Dz 512
#define KTOP 15

typedef __attribute__((ext_vector_type(8))) unsigned short ushort8x;
typedef __attribute__((ext_vector_type(8))) _Float16 half8x;   // fp16x8 MFMA frag
typedef __attribute__((ext_vector_type(4))) float floatx4;     // fp32x4 MFMA acc
typedef __attribute__((ext_vector_type(16))) float float16x;   // fp32x16 MFMA acc (32x32)

// ---------------------------------------------------------------------------
// Transpose-cast the 3 weight matrices (K x N fp32) -> (N x K fp16)
// grid (16,16,3), block (32,8)
// ---------------------------------------------------------------------------
__global__ __launch_bounds__(256) void wtrans3(
    const float* __restrict__ w0, const float* __restrict__ w1,
    const float* __restrict__ w2, _Float16* __restrict__ t0,
    _Float16* __restrict__ t1, _Float16* __restrict__ t2) {
  const float* w = blockIdx.z == 0 ? w0 : (blockIdx.z == 1 ? w1 : w2);
  _Float16* t = blockIdx.z == 0 ? t0 : (blockIdx.z == 1 ? t1 : t2);
  __shared__ float tile[32][33];
  const int n0 = blockIdx.x * 32, k0 = blockIdx.y * 32;
  const int tx = threadIdx.x, ty = threadIdx.y;
  #pragma unroll
  for (int i = 0; i < 4; ++i)
    tile[ty + 8 * i][tx] = w[(size_t)(k0 + ty + 8 * i) * Dz + n0 + tx];
  __syncthreads();
  #pragma unroll
  for (int i = 0; i < 4; ++i)
    t[(size_t)(n0 + ty + 8 * i) * Dz + k0 + tx] = (_Float16)tile[tx][ty + 8 * i];
}

// ---------------------------------------------------------------------------
// Fused MFMA GEMM x3 (Q,K,V in one launch) with XCD-aware work remap:
// flat grid 1536; work = (bid%8)*192 + bid/8 puts the 4 N-tile siblings of
// one A-panel on the SAME XCD (consecutive work ids) -> A fetched once,
// 3x L2 hits. C[m,n] = sum_k A[m,k]*Bt[n,k] + bias[n], written fp16
// TRANSPOSED per batch -> outT[(b*N + n)*2048 + l].
// 128x128 tile, 256 threads (4 waves 2x2), 4x4 frags of 16x16x32, BK=32,
// double-buffered LDS + register prefetch. M=16384, N=K=512.
// ---------------------------------------------------------------------------
#define GLDA 40  // padded LDS row stride (fp16 elems); 80B rows
__global__ __launch_bounds__(256) void gemm3(
    const float* __restrict__ A0, const float* __restrict__ A1,
    const float* __restrict__ A2, const _Float16* __restrict__ B0,
    const _Float16* __restrict__ B1, const _Float16* __restrict__ B2,
    const float* __restrict__ c0, const float* __restrict__ c1,
    const float* __restrict__ c2, _Float16* __restrict__ o0,
    _Float16* __restrict__ o1, _Float16* __restrict__ o2) {
  const int K = Dz;
  // XCD-aware bijective remap (1536 blocks, 8 XCDs, 192 per XCD)
  const int f = blockIdx.x;
  const int work = (f & 7) * 192 + (f >> 3);
  const int z = work >> 9;          // 0..2  (Q,K,V)
  const int rem = work & 511;
  const int mt = rem >> 2;          // 0..127 m-tile
  const int nt = rem & 3;           // 0..3   n-tile
  const float* A = z == 0 ? A0 : (z == 1 ? A1 : A2);
  const _Float16* Bt = z == 0 ? B0 : (z == 1 ? B1 : B2);
  const float* bias = z == 0 ? c0 : (z == 1 ? c1 : c2);
  _Float16* oT = z == 0 ? o0 : (z == 1 ? o1 : o2);

  __shared__ _Float16 smem[20480];  // 40KB: As[2][5120] | Bs[2][5120]
  _Float16* Asb = smem;
  _Float16* Bsb = smem + 10240;
  const int tid = threadIdx.x;
  const int m0 = mt * 128;
  const int n0 = nt * 128;
  const int lane = tid & 63;
  const int wv = tid >> 6;
  const int wr = wv & 1, wc = wv >> 1;
  const int ln = lane & 15;
  const int quad = lane >> 4;

  floatx4 acc[4][4];
  #pragma unroll
  for (int i = 0; i < 4; ++i)
    #pragma unroll
    for (int j = 0; j < 4; ++j) acc[i][j] = (floatx4){0.f, 0.f, 0.f, 0.f};

  float4 ra4[4];
  ushort8x rb[2];

  // prologue: k-tile 0 -> regs -> LDS[0]
  #pragma unroll
  for (int j = 0; j < 4; ++j) {
    const int slot = tid + 256 * j;
    const int r = slot >> 3, c4 = slot & 7;
    ra4[j] = *(const float4*)&A[(size_t)(m0 + r) * K + 4 * c4];
  }
  #pragma unroll
  for (int j = 0; j < 2; ++j) {
    const int slot = tid + 256 * j;
    const int r = slot >> 2, ch = slot & 3;
    rb[j] = *(const ushort8x*)((const unsigned short*)Bt +
                               (size_t)(n0 + r) * K + 8 * ch);
  }
  {
    _Float16* As = Asb;
    _Float16* Bs = Bsb;
    #pragma unroll
    for (int j = 0; j < 4; ++j) {
      const int slot = tid + 256 * j;
      const int r = slot >> 3, c4 = slot & 7;
      union { _Float16 h[4]; unsigned long long u; } p;
      p.h[0] = (_Float16)ra4[j].x;
      p.h[1] = (_Float16)ra4[j].y;
      p.h[2] = (_Float16)ra4[j].z;
      p.h[3] = (_Float16)ra4[j].w;
      *(unsigned long long*)&As[r * GLDA + 4 * c4] = p.u;
    }
    #pragma unroll
    for (int j = 0; j < 2; ++j) {
      const int slot = tid + 256 * j;
      const int r = slot >> 2, ch = slot & 3;
      *(ushort8x*)&Bs[r * GLDA + 8 * ch] = rb[j];
    }
  }
  __syncthreads();

  const int NKT = K / 32;  // 16
  for (int kt = 0; kt < NKT; ++kt) {
    const int cur = kt & 1;
    if (kt + 1 < NKT) {
      const int kof = (kt + 1) * 32;
      #pragma unroll
      for (int j = 0; j < 4; ++j) {
        const int slot = tid + 256 * j;
        const int r = slot >> 3, c4 = slot & 7;
        ra4[j] = *(const float4*)&A[(size_t)(m0 + r) * K + kof + 4 * c4];
      }
      #pragma unroll
      for (int j = 0; j < 2; ++j) {
        const int slot = tid + 256 * j;
        const int r = slot >> 2, ch = slot & 3;
        rb[j] = *(const ushort8x*)((const unsigned short*)Bt +
                                   (size_t)(n0 + r) * K + kof + 8 * ch);
      }
    }
    const _Float16* As = Asb + cur * 5120;
    const _Float16* Bs = Bsb + cur * 5120;
    half8x af[4], bf[4];
    #pragma unroll
    for (int i = 0; i < 4; ++i)
      af[i] = *(const half8x*)&As[(wr * 64 + 16 * i + ln) * GLDA + 8 * quad];
    #pragma unroll
    for (int j = 0; j < 4; ++j)
      bf[j] = *(const half8x*)&Bs[(wc * 64 + 16 * j + ln) * GLDA + 8 * quad];
    #pragma unroll
    for (int i = 0; i < 4; ++i)
      #pragma unroll
      for (int j = 0; j < 4; ++j)
        acc[i][j] = __builtin_amdgcn_mfma_f32_16x16x32_f16(af[i], bf[j], acc[i][j], 0, 0, 0);
    if (kt + 1 < NKT) {
      const int nxt = cur ^ 1;
      _Float16* Asw = Asb + nxt * 5120;
      _Float16* Bsw = Bsb + nxt * 5120;
      #pragma unroll
      for (int j = 0; j < 4; ++j) {
        const int slot = tid + 256 * j;
        const int r = slot >> 3, c4 = slot & 7;
        union { _Float16 h[4]; unsigned long long u; } p;
        p.h[0] = (_Float16)ra4[j].x;
        p.h[1] = (_Float16)ra4[j].y;
        p.h[2] = (_Float16)ra4[j].z;
        p.h[3] = (_Float16)ra4[j].w;
        *(unsigned long long*)&Asw[r * GLDA + 4 * c4] = p.u;
      }
      #pragma unroll
      for (int j = 0; j < 2; ++j) {
        const int slot = tid + 256 * j;
        const int r = slot >> 2, ch = slot & 3;
        *(ushort8x*)&Bsw[r * GLDA + 8 * ch] = rb[j];
      }
      __syncthreads();
    }
  }

  // epilogue: retranspose through LDS, write fp16 (B, N, L) layout
  __syncthreads();                 // all LDS frag reads done
  _Float16* TB = smem;             // [128][136] fp16 = 34816 B <= 40KB
  #pragma unroll
  for (int j = 0; j < 4; ++j) {
    const int n_l = wc * 64 + 16 * j + ln;
    const float bv = bias[n0 + n_l];
    #pragma unroll
    for (int i = 0; i < 4; ++i) {
      const int m_l = wr * 64 + 16 * i + 4 * quad;
      union { _Float16 h[4]; unsigned long long u; } p;
      #pragma unroll
      for (int r = 0; r < 4; ++r) p.h[r] = (_Float16)(acc[i][j][r] + bv);
      *(unsigned long long*)&TB[n_l * 136 + m_l] = p.u;
    }
  }
  __syncthreads();
  const int b = m0 >> 11;
  const int l0 = m0 & 2047;
  #pragma unroll
  for (int it = 0; it < 8; ++it) {
    const int s = tid + 256 * it;
    const int n = s >> 4, c = s & 15;
    *(ushort8x*)(oT + ((size_t)(b * Dz + n0 + n)) * Lz + l0 + 8 * c) =
        *(const ushort8x*)&TB[n * 136 + 8 * c];
  }
}

// ---------------------------------------------------------------------------
// Per-channel circular correlation via fp16 32x32x16 MFMA + ballot top-15.
// One block (256 threads, 4 waves) per (b,d) channel.  (unchanged)
// ---------------------------------------------------------------------------
#define QXS 2072  // halves per shifted copy; 4144 B = 259 x 16B slots (259 odd)

__device__ __forceinline__ int swz128(int byte) {
  return byte ^ (((byte >> 7) & 7) << 4);
}

__global__ __launch_bounds__(256) void corr_mfma_topk(
    const _Float16* __restrict__ qT, const _Float16* __restrict__ kT,
    float* __restrict__ Wk, int* __restrict__ Ik) {
  __shared__ __attribute__((aligned(16))) unsigned short qx[8 * QXS];
  __shared__ __attribute__((aligned(16))) unsigned short ke[Lz];
  __shared__ float cv[64];
  __shared__ int ci[64];

  const int tid = threadIdx.x;
  const size_t chan = (size_t)blockIdx.x * Lz;
  const unsigned short* qg = (const unsigned short*)(qT + chan);
  const unsigned short* kg = (const unsigned short*)(kT + chan);

  {
    ushort8x v = *(const ushort8x*)(kg + 8 * tid);
    *(ushort8x*)((char*)ke + swz128(16 * tid)) = v;
  }
  for (int c = tid; c < QXS / 8; c += 256) {  // 259 slots
    union { unsigned int d[8]; ushort8x v[2]; } b;
    b.v[0] = *(const ushort8x*)(qg + ((8 * c) & (Lz - 1)));
    b.v[1] = *(const ushort8x*)(qg + ((8 * c + 8) & (Lz - 1)));
    #pragma unroll
    for (int s = 0; s < 8; ++s) {
      union { unsigned int d[4]; ushort8x v; } w;
      if (s & 1) {
        #pragma unroll
        for (int t = 0; t < 4; ++t)
          w.d[t] = __builtin_amdgcn_alignbit(b.d[(s >> 1) + t + 1],
                                             b.d[(s >> 1) + t], 16);
      } else {
        #pragma unroll
        for (int t = 0; t < 4; ++t) w.d[t] = b.d[(s >> 1) + t];
      }
      *(ushort8x*)&qx[s * QXS + 8 * c] = w.v;
    }
  }
  __syncthreads();

  const int lane = tid & 63;
  const int wv = tid >> 6;
  const int jb = lane & 31;
  const int hi = lane >> 5;
  const char* aptr = (const char*)qx + (jb & 7) * (2 * QXS) + 16 * (jb >> 3) + 16 * hi;
  const int bb2 = ((8 * hi - 32 * jb) & (Lz - 1)) * 2;

  float16x acc0 = {0.f, 0.f, 0.f, 0.f, 0.f, 0.f, 0.f, 0.f,
                   0.f, 0.f, 0.f, 0.f, 0.f, 0.f, 0.f, 0.f};
  float16x acc1 = acc0;

  const int t0base = wv << 9;
  #pragma unroll 4
  for (int it = 0; it < 32; ++it) {
    const int t2 = 2 * (t0base + 16 * it);
    half8x a = *(const half8x*)(aptr + t2);
    const int y0 = (bb2 + t2) & (2 * Lz - 1);
    const int y1 = (y0 + 2048) & (2 * Lz - 1);
    half8x b0 = *(const half8x*)((const char*)ke + swz128(y0));
    half8x b1 = *(const half8x*)((const char*)ke + swz128(y1));
    acc0 = __builtin_amdgcn_mfma_f32_32x32x16_f16(a, b0, acc0, 0, 0, 0);
    acc1 = __builtin_amdgcn_mfma_f32_32x32x16_f16(a, b1, acc1, 0, 0, 0);
  }

  __syncthreads();
  float* red = (float*)qx;
  {
    const int rbase = wv * 8192;
    #pragma unroll
    for (int g = 0; g < 4; ++g) {
      const int tau0 = 8 * g + 4 * hi + 32 * jb;
      float4 p0, p1;
      p0.x = acc0[4 * g + 0]; p0.y = acc0[4 * g + 1];
      p0.z = acc0[4 * g + 2]; p0.w = acc0[4 * g + 3];
      p1.x = acc1[4 * g + 0]; p1.y = acc1[4 * g + 1];
      p1.z = acc1[4 * g + 2]; p1.w = acc1[4 * g + 3];
      *(float4*)((char*)red + swz128(rbase + 4 * tau0)) = p0;
      *(float4*)((char*)red + swz128(rbase + 4 * (tau0 + 1024))) = p1;
    }
  }
  __syncthreads();

  float vals[8] = {0.f, 0.f, 0.f, 0.f, 0.f, 0.f, 0.f, 0.f};
  {
    const char* rb = (const char*)red;
    #pragma unroll
    for (int w = 0; w < 4; ++w) {
      float4 a0 = *(const float4*)(rb + swz128(w * 8192 + 32 * tid));
      float4 a1 = *(const float4*)(rb + swz128(w * 8192 + 32 * tid + 16));
      vals[0] += a0.x; vals[1] += a0.y; vals[2] += a0.z; vals[3] += a0.w;
      vals[4] += a1.x; vals[5] += a1.y; vals[6] += a1.z; vals[7] += a1.w;
    }
  }

  unsigned key[8];
  #pragma unroll
  for (int j = 0; j < 8; ++j) {
    const unsigned u = __float_as_uint(vals[j]);
    key[j] = u ^ (unsigned)(((int)u >> 31) | 0x80000000);
  }
  unsigned p = 0;
  for (int b = 31; b >= 0; --b) {
    const unsigned c = p | (1u << b);
    int cnt = 0;
    #pragma unroll
    for (int j = 0; j < 8; ++j)
      cnt += __popcll(__ballot(key[j] >= c));
    if (cnt >= KTOP) p = c;
  }
  const unsigned long long ltm = (1ull << lane) - 1ull;
  int base = 0;
  #pragma unroll
  for (int j = 0; j < 8; ++j) {
    const bool g = key[j] > p;
    const unsigned long long m = __ballot(g);
    const int pos = base + __popcll(m & ltm);
    if (g) { cv[wv * KTOP + pos] = vals[j]; ci[wv * KTOP + pos] = 8 * tid + j; }
    base += __popcll(m);
  }
  #pragma unroll
  for (int j = 0; j < 8; ++j) {
    const bool e = (key[j] == p);
    const unsigned long long m = __ballot(e);
    const int pos = base + __popcll(m & ltm);
    if (e && pos < KTOP) { cv[wv * KTOP + pos] = vals[j]; ci[wv * KTOP + pos] = 8 * tid + j; }
    base += __popcll(m);
  }
  __syncthreads();

  if (wv == 0) {
    const bool act = lane < 4 * KTOP;
    const float v = act ? cv[lane] : 0.f;
    const int ti = act ? ci[lane] : 0;
    unsigned k2 = 0;
    if (act) {
      const unsigned u = __float_as_uint(v);
      k2 = u ^ (unsigned)(((int)u >> 31) | 0x80000000);
    }
    unsigned pp = 0;
    for (int b = 31; b >= 0; --b) {
      const unsigned c = pp | (1u << b);
      if (__popcll(__ballot(k2 >= c)) >= KTOP) pp = c;
    }
    const unsigned long long mg = __ballot(k2 > pp);
    const int tot = __popcll(mg);
    bool sel = (k2 > pp);
    int pos = __popcll(mg & ltm);
    const unsigned long long me = __ballot(k2 == pp);
    const int pose = tot + __popcll(me & ltm);
    if (k2 == pp && pose < KTOP) { sel = true; pos = pose; }
    if (sel) { cv[pos] = v; ci[pos] = ti; }
    const float sv = (lane < KTOP) ? cv[lane] : -3.0e38f;
    const int si = (lane < KTOP) ? ci[lane] : 0;
    float gm = sv;
    #pragma unroll
    for (int off = 1; off < 64; off <<= 1)
      gm = fmaxf(gm, __shfl_xor(gm, off, 64));
    float e = (lane < KTOP) ? expf(sv - gm) : 0.f;
    float es = e;
    #pragma unroll
    for (int off = 1; off < 64; off <<= 1) es += __shfl_xor(es, off, 64);
    if (lane < KTOP) {
      const size_t ob = (size_t)blockIdx.x * KTOP;
      Wk[ob + lane] = e / es;
      Ik[ob + lane] = si;
    }
  }
}

// ---------------------------------------------------------------------------
// Fused gather v2: out[b,l,d] = sum_k w[b,d,k] * vT[b,d,(l+I[b,d,k]) mod L]
// vT is fp16 (B,D,L). Block = 8 d-channels, 256 threads, grid (D/8, B).
// ---------------------------------------------------------------------------
#define GSWZ(b) ((b) ^ ((((b) >> 12) & 7) << 4))  // XOR slot bits 0..2 with dl

__global__ __launch_bounds__(256) void gather_fused(
    const _Float16* __restrict__ vT, const float* __restrict__ Wk,
    const int* __restrict__ Ik, float* __restrict__ out) {
  __shared__ __attribute__((aligned(16))) _Float16 ls[8 * Lz];  // 32 KB swizzled
  __shared__ float os[256 * 9];                                 // 9 KB out-staging
  const int tid = threadIdx.x;
  const int d0 = blockIdx.x * 8;
  const int b = blockIdx.y;
  float* ob = out + (size_t)b * Lz * Dz;

  // stage vT[b, d0..d0+8, :] -> ls (swizzled), 16B granules
  const char* lsb = (const char*)ls;
  #pragma unroll
  for (int it = 0; it < 8; ++it) {
    const int slot = tid + 256 * it;          // 2048 slots of 16B
    const int dl2 = slot >> 8, c = slot & 255;
    ushort8x v = *(const ushort8x*)((const unsigned short*)vT +
                                    ((size_t)(b * Dz + d0 + dl2) * Lz) + 8 * c);
    *(ushort8x*)((char*)ls + GSWZ(16 * slot)) = v;
  }

  const int dl = tid & 7;
  const int lg = tid >> 3;  // [0,32)
  const size_t wb = ((size_t)b * Dz + d0 + dl) * KTOP;
  float wreg[KTOP];
  int ireg[KTOP];
  #pragma unroll
  for (int k = 0; k < KTOP; ++k) {
    wreg[k] = Wk[wb + k];
    ireg[k] = Ik[wb + k];
  }
  __syncthreads();

  const int rowb = dl * 4096;  // byte base of this lane's row
  for (int lt = 0; lt < 8; ++lt) {
    const int lbase = lt * 256 + lg * 8;
    float acc[8] = {0.f, 0.f, 0.f, 0.f, 0.f, 0.f, 0.f, 0.f};
    for (int k = 0; k < KTOP; ++k) {
      const float w = wreg[k];
      const int p = (lbase + ireg[k]) & (Lz - 1);
      const int b0 = p >> 3;
      const int b1 = (b0 + 1) & 255;
      union { ushort8x v; unsigned d[4]; } A0, A1;
      A0.v = *(const ushort8x*)(lsb + GSWZ(rowb + 16 * b0));
      A1.v = *(const ushort8x*)(lsb + GSWZ(rowb + 16 * b1));
      const int h = p & 7;
      unsigned e0, e1, e2, e3, e4, e5;
      if (h & 4) { e0 = A0.d[2]; e1 = A0.d[3]; e2 = A1.d[0]; e3 = A1.d[1]; e4 = A1.d[2]; e5 = A1.d[3]; }
      else       { e0 = A0.d[0]; e1 = A0.d[1]; e2 = A0.d[2]; e3 = A0.d[3]; e4 = A1.d[0]; e5 = A1.d[1]; }
      unsigned f0, f1, f2, f3, f4;
      if (h & 2) { f0 = e1; f1 = e2; f2 = e3; f3 = e4; f4 = e5; }
      else       { f0 = e0; f1 = e1; f2 = e2; f3 = e3; f4 = e4; }
      const int sh = (h & 1) << 4;
      unsigned o0 = __builtin_amdgcn_alignbit(f1, f0, sh);
      unsigned o1 = __builtin_amdgcn_alignbit(f2, f1, sh);
      unsigned o2 = __builtin_amdgcn_alignbit(f3, f2, sh);
      unsigned o3 = __builtin_amdgcn_alignbit(f4, f3, sh);
      union { unsigned u; _Float16 hh[2]; } c0, c1, c2, c3;
      c0.u = o0; c1.u = o1; c2.u = o2; c3.u = o3;
      acc[0] += w * (float)c0.hh[0]; acc[1] += w * (float)c0.hh[1];
      acc[2] += w * (float)c1.hh[0]; acc[3] += w * (float)c1.hh[1];
      acc[4] += w * (float)c2.hh[0]; acc[5] += w * (float)c2.hh[1];
      acc[6] += w * (float)c3.hh[0]; acc[7] += w * (float)c3.hh[1];
    }
    __syncthreads();  // previous tile's os reads complete
    #pragma unroll
    for (int j = 0; j < 8; ++j) os[(lg * 8 + j) * 9 + dl] = acc[j];
    __syncthreads();
    #pragma unroll
    for (int c2 = 0; c2 < 2; ++c2) {
      const int sl = tid + 256 * c2;  // 512 slots
      const int l = sl >> 1, c = sl & 1;
      float4 o;
      o.x = os[l * 9 + 4 * c + 0];
      o.y = os[l * 9 + 4 * c + 1];
      o.z = os[l * 9 + 4 * c + 2];
      o.w = os[l * 9 + 4 * c + 3];
      *(float4*)&ob[(size_t)(lt * 256 + l) * Dz + d0 + 4 * c] = o;
    }
  }
}

// ---------------------------------------------------------------------------
extern "C" void kernel_launch(void* const* d_in, const int* in_sizes, int n_in,
                              void* d_out, int out_size, void* d_ws, size_t ws_size,
                              hipStream_t stream) {
  const float* Q = (const float*)d_in[0];
  const float* K = (const float*)d_in[1];
  const float* V = (const float*)d_in[2];
  const float* WQw = (const float*)d_in[3];
  const float* WQb = (const float*)d_in[4];
  const float* WKw = (const float*)d_in[5];
  const float* WKb = (const float*)d_in[6];
  const float* WVw = (const float*)d_in[7];
  const float* WVb = (const float*)d_in[8];
  float* out = (float*)d_out;

  const size_t CH = (size_t)Bz * Dz;        // 4096
  const size_t NEL = (size_t)Bz * Lz * Dz;  // 8388608

  char* ws = (char*)d_ws;
  _Float16* qT = (_Float16*)ws;                      // NEL fp16 (B,D,L)
  _Float16* kT = qT + NEL;                           // NEL fp16
  _Float16* vT = kT + NEL;                           // NEL fp16 (B,D,L)
  _Float16* WQt = vT + NEL;                          // 512x512 fp16 each
  _Float16* WKt = WQt + (size_t)Dz * Dz;
  _Float16* WVt = WKt + (size_t)Dz * Dz;
  float* Wk = (float*)(WVt + (size_t)Dz * Dz);
  int* Ik = (int*)(Wk + CH * KTOP);

  dim3 tr_block(32, 8);

  // weights -> fp16 transposed (N x K)
  wtrans3<<<dim3(16, 16, 3), tr_block, 0, stream>>>(WQw, WKw, WVw, WQt, WKt, WVt);

  // q, k, v -> fp16 transposed (B,D,L), single merged launch, XCD-remapped
  gemm3<<<dim3(1536), dim3(256), 0, stream>>>(
      Q, K, V, WQt, WKt, WVt, WQb, WKb, WVb, qT, kT, vT);

  // correlation (MFMA) + top-k + softmax per channel
  corr_mfma_topk<<<dim3((unsigned)CH), dim3(256), 0, stream>>>(qT, kT, Wk, Ik);

  // fused gather -> out (B,L,D)
  gather_fused<<<dim3(Dz / 8, Bz), dim3(256), 0, stream>>>(vT, Wk, Ik, out);
}

// Round 4
// 272.089 us; speedup vs baseline: 1.0006x; 1.0006x over previous
//
#include <hip/hip_runtime.h>
#include <hip/hip_bf16.h>
#include <math.h>

// Problem constants
#define Bz 8
#define Lz 2048
#define Dz 512
#define KTOP 15

typedef __attribute__((ext_vector_type(8))) unsigned short ushort8x;
typedef __attribute__((ext_vector_type(8))) _Float16 half8x;   // fp16x8 MFMA frag
typedef __attribute__((ext_vector_type(4))) float floatx4;     // fp32x4 MFMA acc
typedef __attribute__((ext_vector_type(16))) float float16x;   // fp32x16 MFMA acc (32x32)

// ---------------------------------------------------------------------------
// Transpose-cast the 3 weight matrices (K x N fp32) -> (N x K fp16)
// grid (16,16,3), block (32,8)
// ---------------------------------------------------------------------------
__global__ __launch_bounds__(256) void wtrans3(
    const float* __restrict__ w0, const float* __restrict__ w1,
    const float* __restrict__ w2, _Float16* __restrict__ t0,
    _Float16* __restrict__ t1, _Float16* __restrict__ t2) {
  const float* w = blockIdx.z == 0 ? w0 : (blockIdx.z == 1 ? w1 : w2);
  _Float16* t = blockIdx.z == 0 ? t0 : (blockIdx.z == 1 ? t1 : t2);
  __shared__ float tile[32][33];
  const int n0 = blockIdx.x * 32, k0 = blockIdx.y * 32;
  const int tx = threadIdx.x, ty = threadIdx.y;
  #pragma unroll
  for (int i = 0; i < 4; ++i)
    tile[ty + 8 * i][tx] = w[(size_t)(k0 + ty + 8 * i) * Dz + n0 + tx];
  __syncthreads();
  #pragma unroll
  for (int i = 0; i < 4; ++i)
    t[(size_t)(n0 + ty + 8 * i) * Dz + k0 + tx] = (_Float16)tile[tx][ty + 8 * i];
}

// ---------------------------------------------------------------------------
// Fused MFMA GEMM x3 (Q,K,V in one launch; blockIdx.z selects operand set):
// C[m,n] = sum_k A[m,k]*Bt[n,k] + bias[n], written fp16 TRANSPOSED per batch
// -> outT[(b*N + n)*2048 + l].
// A: M x K fp32 (cast fp16 during reg->LDS staging, padded rows).
// B: N x K fp16, staged via global_load_lds width-16 into a LINEAR LDS tile;
//    bank spread achieved by pre-swizzling the per-lane GLOBAL source
//    (qs = q ^ (row&3)) and applying the same XOR on the read side.
// Epilogue: direct packed 8B stores (no LDS retranspose, no barriers).
// 128x128 tile, 256 threads (4 waves 2x2), 4x4 frags of 16x16x32, BK=32,
// double-buffered LDS. M=16384, N=K=512. grid (4,128,3).
// ---------------------------------------------------------------------------
#define ALDA 40  // padded LDS row stride for A (fp16 elems); 80B rows
__global__ __launch_bounds__(256) void gemm3(
    const float* __restrict__ A0, const float* __restrict__ A1,
    const float* __restrict__ A2, const _Float16* __restrict__ B0,
    const _Float16* __restrict__ B1, const _Float16* __restrict__ B2,
    const float* __restrict__ c0, const float* __restrict__ c1,
    const float* __restrict__ c2, _Float16* __restrict__ o0,
    _Float16* __restrict__ o1, _Float16* __restrict__ o2) {
  const int K = Dz;
  const int z = blockIdx.z;
  const float* A = z == 0 ? A0 : (z == 1 ? A1 : A2);
  const _Float16* Bt = z == 0 ? B0 : (z == 1 ? B1 : B2);
  const float* bias = z == 0 ? c0 : (z == 1 ? c1 : c2);
  _Float16* oT = z == 0 ? o0 : (z == 1 ? o1 : o2);

  __shared__ __attribute__((aligned(16))) _Float16 smem[18432];  // 36KB
  _Float16* Asb = smem;          // [2][128*40]
  _Float16* Bsb = smem + 10240;  // [2][128*32] linear
  const int tid = threadIdx.x;
  const int m0 = blockIdx.y * 128;
  const int n0 = blockIdx.x * 128;
  const int lane = tid & 63;
  const int wv = tid >> 6;
  const int wr = wv & 1, wc = wv >> 1;
  const int ln = lane & 15;
  const int quad = lane >> 4;

  floatx4 acc[4][4];
  #pragma unroll
  for (int i = 0; i < 4; ++i)
    #pragma unroll
    for (int j = 0; j < 4; ++j) acc[i][j] = (floatx4){0.f, 0.f, 0.f, 0.f};

  float4 ra4[4];

  // B staging slot decode (per jj in 0..1): s = tid + 256*jj
  //   row = s>>2, q = s&3, qs = q^(row&3)  (source pre-swizzle)
  //   LDS dest is linear: halves [8*s, 8*s+8)
  // prologue: k-tile 0
  #pragma unroll
  for (int j = 0; j < 4; ++j) {
    const int slot = tid + 256 * j;
    const int r = slot >> 3, c4 = slot & 7;
    ra4[j] = *(const float4*)&A[(size_t)(m0 + r) * K + 4 * c4];
  }
  #pragma unroll
  for (int jj = 0; jj < 2; ++jj) {
    const int s = tid + 256 * jj;
    const int row = s >> 2;
    const int qs = (s & 3) ^ (row & 3);
    const unsigned short* src =
        (const unsigned short*)Bt + (size_t)(n0 + row) * K + 8 * qs;
    __builtin_amdgcn_global_load_lds(
        (const __attribute__((address_space(1))) unsigned int*)src,
        (__attribute__((address_space(3))) unsigned int*)&Bsb[(jj * 256 + wv * 64) * 8],
        16, 0, 0);
  }
  #pragma unroll
  for (int j = 0; j < 4; ++j) {
    const int slot = tid + 256 * j;
    const int r = slot >> 3, c4 = slot & 7;
    union { _Float16 h[4]; unsigned long long u; } p;
    p.h[0] = (_Float16)ra4[j].x;
    p.h[1] = (_Float16)ra4[j].y;
    p.h[2] = (_Float16)ra4[j].z;
    p.h[3] = (_Float16)ra4[j].w;
    *(unsigned long long*)&Asb[r * ALDA + 4 * c4] = p.u;
  }
  __syncthreads();

  const int NKT = K / 32;  // 16
  for (int kt = 0; kt < NKT; ++kt) {
    const int cur = kt & 1;
    const int nxt = cur ^ 1;
    if (kt + 1 < NKT) {
      const int kof = (kt + 1) * 32;
      // issue A global loads early (consumed at bottom of loop)
      #pragma unroll
      for (int j = 0; j < 4; ++j) {
        const int slot = tid + 256 * j;
        const int r = slot >> 3, c4 = slot & 7;
        ra4[j] = *(const float4*)&A[(size_t)(m0 + r) * K + kof + 4 * c4];
      }
      // issue B DMA into next buffer (overlaps frag reads + MFMA)
      #pragma unroll
      for (int jj = 0; jj < 2; ++jj) {
        const int s = tid + 256 * jj;
        const int row = s >> 2;
        const int qs = (s & 3) ^ (row & 3);
        const unsigned short* src =
            (const unsigned short*)Bt + (size_t)(n0 + row) * K + kof + 8 * qs;
        __builtin_amdgcn_global_load_lds(
            (const __attribute__((address_space(1))) unsigned int*)src,
            (__attribute__((address_space(3))) unsigned int*)
                &Bsb[nxt * 4096 + (jj * 256 + wv * 64) * 8],
            16, 0, 0);
      }
    }
    const _Float16* As = Asb + cur * 5120;
    const _Float16* Bs = Bsb + cur * 4096;
    half8x af[4], bf[4];
    #pragma unroll
    for (int i = 0; i < 4; ++i)
      af[i] = *(const half8x*)&As[(wr * 64 + 16 * i + ln) * ALDA + 8 * quad];
    #pragma unroll
    for (int j = 0; j < 4; ++j) {
      const int row = wc * 64 + 16 * j + ln;
      bf[j] = *(const half8x*)&Bs[row * 32 + 8 * (quad ^ (ln & 3))];
    }
    #pragma unroll
    for (int i = 0; i < 4; ++i)
      #pragma unroll
      for (int j = 0; j < 4; ++j)
        acc[i][j] = __builtin_amdgcn_mfma_f32_16x16x32_f16(af[i], bf[j], acc[i][j], 0, 0, 0);
    if (kt + 1 < NKT) {
      _Float16* Asw = Asb + nxt * 5120;
      #pragma unroll
      for (int j = 0; j < 4; ++j) {
        const int slot = tid + 256 * j;
        const int r = slot >> 3, c4 = slot & 7;
        union { _Float16 h[4]; unsigned long long u; } p;
        p.h[0] = (_Float16)ra4[j].x;
        p.h[1] = (_Float16)ra4[j].y;
        p.h[2] = (_Float16)ra4[j].z;
        p.h[3] = (_Float16)ra4[j].w;
        *(unsigned long long*)&Asw[r * ALDA + 4 * c4] = p.u;
      }
      __syncthreads();
    }
  }

  // epilogue: direct packed stores, fp16 (B, N, L) layout; no LDS, no barrier
  const int bb = m0 >> 11;
  const int l0 = m0 & 2047;
  #pragma unroll
  for (int j = 0; j < 4; ++j) {
    const int d = n0 + wc * 64 + 16 * j + ln;
    const float bv = bias[d];
    _Float16* op = oT + (size_t)(bb * Dz + d) * Lz + l0 + wr * 64 + 4 * quad;
    #pragma unroll
    for (int i = 0; i < 4; ++i) {
      union { _Float16 h[4]; unsigned long long u; } p;
      #pragma unroll
      for (int r = 0; r < 4; ++r) p.h[r] = (_Float16)(acc[i][j][r] + bv);
      *(unsigned long long*)(op + 16 * i) = p.u;
    }
  }
}

// ---------------------------------------------------------------------------
// Per-channel circular correlation via fp16 32x32x16 MFMA + ballot top-15.
// One block (256 threads, 4 waves) per (b,d) channel.  (unchanged)
// ---------------------------------------------------------------------------
#define QXS 2072  // halves per shifted copy; 4144 B = 259 x 16B slots (259 odd)

__device__ __forceinline__ int swz128(int byte) {
  return byte ^ (((byte >> 7) & 7) << 4);
}

__global__ __launch_bounds__(256) void corr_mfma_topk(
    const _Float16* __restrict__ qT, const _Float16* __restrict__ kT,
    float* __restrict__ Wk, int* __restrict__ Ik) {
  __shared__ __attribute__((aligned(16))) unsigned short qx[8 * QXS];
  __shared__ __attribute__((aligned(16))) unsigned short ke[Lz];
  __shared__ float cv[64];
  __shared__ int ci[64];

  const int tid = threadIdx.x;
  const size_t chan = (size_t)blockIdx.x * Lz;
  const unsigned short* qg = (const unsigned short*)(qT + chan);
  const unsigned short* kg = (const unsigned short*)(kT + chan);

  {
    ushort8x v = *(const ushort8x*)(kg + 8 * tid);
    *(ushort8x*)((char*)ke + swz128(16 * tid)) = v;
  }
  for (int c = tid; c < QXS / 8; c += 256) {  // 259 slots
    union { unsigned int d[8]; ushort8x v[2]; } b;
    b.v[0] = *(const ushort8x*)(qg + ((8 * c) & (Lz - 1)));
    b.v[1] = *(const ushort8x*)(qg + ((8 * c + 8) & (Lz - 1)));
    #pragma unroll
    for (int s = 0; s < 8; ++s) {
      union { unsigned int d[4]; ushort8x v; } w;
      if (s & 1) {
        #pragma unroll
        for (int t = 0; t < 4; ++t)
          w.d[t] = __builtin_amdgcn_alignbit(b.d[(s >> 1) + t + 1],
                                             b.d[(s >> 1) + t], 16);
      } else {
        #pragma unroll
        for (int t = 0; t < 4; ++t) w.d[t] = b.d[(s >> 1) + t];
      }
      *(ushort8x*)&qx[s * QXS + 8 * c] = w.v;
    }
  }
  __syncthreads();

  const int lane = tid & 63;
  const int wv = tid >> 6;
  const int jb = lane & 31;
  const int hi = lane >> 5;
  const char* aptr = (const char*)qx + (jb & 7) * (2 * QXS) + 16 * (jb >> 3) + 16 * hi;
  const int bb2 = ((8 * hi - 32 * jb) & (Lz - 1)) * 2;

  float16x acc0 = {0.f, 0.f, 0.f, 0.f, 0.f, 0.f, 0.f, 0.f,
                   0.f, 0.f, 0.f, 0.f, 0.f, 0.f, 0.f, 0.f};
  float16x acc1 = acc0;

  const int t0base = wv << 9;
  #pragma unroll 4
  for (int it = 0; it < 32; ++it) {
    const int t2 = 2 * (t0base + 16 * it);
    half8x a = *(const half8x*)(aptr + t2);
    const int y0 = (bb2 + t2) & (2 * Lz - 1);
    const int y1 = (y0 + 2048) & (2 * Lz - 1);
    half8x b0 = *(const half8x*)((const char*)ke + swz128(y0));
    half8x b1 = *(const half8x*)((const char*)ke + swz128(y1));
    acc0 = __builtin_amdgcn_mfma_f32_32x32x16_f16(a, b0, acc0, 0, 0, 0);
    acc1 = __builtin_amdgcn_mfma_f32_32x32x16_f16(a, b1, acc1, 0, 0, 0);
  }

  __syncthreads();
  float* red = (float*)qx;
  {
    const int rbase = wv * 8192;
    #pragma unroll
    for (int g = 0; g < 4; ++g) {
      const int tau0 = 8 * g + 4 * hi + 32 * jb;
      float4 p0, p1;
      p0.x = acc0[4 * g + 0]; p0.y = acc0[4 * g + 1];
      p0.z = acc0[4 * g + 2]; p0.w = acc0[4 * g + 3];
      p1.x = acc1[4 * g + 0]; p1.y = acc1[4 * g + 1];
      p1.z = acc1[4 * g + 2]; p1.w = acc1[4 * g + 3];
      *(float4*)((char*)red + swz128(rbase + 4 * tau0)) = p0;
      *(float4*)((char*)red + swz128(rbase + 4 * (tau0 + 1024))) = p1;
    }
  }
  __syncthreads();

  float vals[8] = {0.f, 0.f, 0.f, 0.f, 0.f, 0.f, 0.f, 0.f};
  {
    const char* rb = (const char*)red;
    #pragma unroll
    for (int w = 0; w < 4; ++w) {
      float4 a0 = *(const float4*)(rb + swz128(w * 8192 + 32 * tid));
      float4 a1 = *(const float4*)(rb + swz128(w * 8192 + 32 * tid + 16));
      vals[0] += a0.x; vals[1] += a0.y; vals[2] += a0.z; vals[3] += a0.w;
      vals[4] += a1.x; vals[5] += a1.y; vals[6] += a1.z; vals[7] += a1.w;
    }
  }

  unsigned key[8];
  #pragma unroll
  for (int j = 0; j < 8; ++j) {
    const unsigned u = __float_as_uint(vals[j]);
    key[j] = u ^ (unsigned)(((int)u >> 31) | 0x80000000);
  }
  unsigned p = 0;
  for (int b = 31; b >= 0; --b) {
    const unsigned c = p | (1u << b);
    int cnt = 0;
    #pragma unroll
    for (int j = 0; j < 8; ++j)
      cnt += __popcll(__ballot(key[j] >= c));
    if (cnt >= KTOP) p = c;
  }
  const unsigned long long ltm = (1ull << lane) - 1ull;
  int base = 0;
  #pragma unroll
  for (int j = 0; j < 8; ++j) {
    const bool g = key[j] > p;
    const unsigned long long m = __ballot(g);
    const int pos = base + __popcll(m & ltm);
    if (g) { cv[wv * KTOP + pos] = vals[j]; ci[wv * KTOP + pos] = 8 * tid + j; }
    base += __popcll(m);
  }
  #pragma unroll
  for (int j = 0; j < 8; ++j) {
    const bool e = (key[j] == p);
    const unsigned long long m = __ballot(e);
    const int pos = base + __popcll(m & ltm);
    if (e && pos < KTOP) { cv[wv * KTOP + pos] = vals[j]; ci[wv * KTOP + pos] = 8 * tid + j; }
    base += __popcll(m);
  }
  __syncthreads();

  if (wv == 0) {
    const bool act = lane < 4 * KTOP;
    const float v = act ? cv[lane] : 0.f;
    const int ti = act ? ci[lane] : 0;
    unsigned k2 = 0;
    if (act) {
      const unsigned u = __float_as_uint(v);
      k2 = u ^ (unsigned)(((int)u >> 31) | 0x80000000);
    }
    unsigned pp = 0;
    for (int b = 31; b >= 0; --b) {
      const unsigned c = pp | (1u << b);
      if (__popcll(__ballot(k2 >= c)) >= KTOP) pp = c;
    }
    const unsigned long long mg = __ballot(k2 > pp);
    const int tot = __popcll(mg);
    bool sel = (k2 > pp);
    int pos = __popcll(mg & ltm);
    const unsigned long long me = __ballot(k2 == pp);
    const int pose = tot + __popcll(me & ltm);
    if (k2 == pp && pose < KTOP) { sel = true; pos = pose; }
    if (sel) { cv[pos] = v; ci[pos] = ti; }
    const float sv = (lane < KTOP) ? cv[lane] : -3.0e38f;
    const int si = (lane < KTOP) ? ci[lane] : 0;
    float gm = sv;
    #pragma unroll
    for (int off = 1; off < 64; off <<= 1)
      gm = fmaxf(gm, __shfl_xor(gm, off, 64));
    float e = (lane < KTOP) ? expf(sv - gm) : 0.f;
    float es = e;
    #pragma unroll
    for (int off = 1; off < 64; off <<= 1) es += __shfl_xor(es, off, 64);
    if (lane < KTOP) {
      const size_t ob = (size_t)blockIdx.x * KTOP;
      Wk[ob + lane] = e / es;
      Ik[ob + lane] = si;
    }
  }
}

// ---------------------------------------------------------------------------
// Fused gather v2: out[b,l,d] = sum_k w[b,d,k] * vT[b,d,(l+I[b,d,k]) mod L]
// vT is fp16 (B,D,L). Block = 8 d-channels, 256 threads, grid (D/8, B).
// ---------------------------------------------------------------------------
#define GSWZ(b) ((b) ^ ((((b) >> 12) & 7) << 4))  // XOR slot bits 0..2 with dl

__global__ __launch_bounds__(256) void gather_fused(
    const _Float16* __restrict__ vT, const float* __restrict__ Wk,
    const int* __restrict__ Ik, float* __restrict__ out) {
  __shared__ __attribute__((aligned(16))) _Float16 ls[8 * Lz];  // 32 KB swizzled
  __shared__ float os[256 * 9];                                 // 9 KB out-staging
  const int tid = threadIdx.x;
  const int d0 = blockIdx.x * 8;
  const int b = blockIdx.y;
  float* ob = out + (size_t)b * Lz * Dz;

  // stage vT[b, d0..d0+8, :] -> ls (swizzled), 16B granules
  const char* lsb = (const char*)ls;
  #pragma unroll
  for (int it = 0; it < 8; ++it) {
    const int slot = tid + 256 * it;          // 2048 slots of 16B
    const int dl2 = slot >> 8, c = slot & 255;
    ushort8x v = *(const ushort8x*)((const unsigned short*)vT +
                                    ((size_t)(b * Dz + d0 + dl2) * Lz) + 8 * c);
    *(ushort8x*)((char*)ls + GSWZ(16 * slot)) = v;
  }

  const int dl = tid & 7;
  const int lg = tid >> 3;  // [0,32)
  const size_t wb = ((size_t)b * Dz + d0 + dl) * KTOP;
  float wreg[KTOP];
  int ireg[KTOP];
  #pragma unroll
  for (int k = 0; k < KTOP; ++k) {
    wreg[k] = Wk[wb + k];
    ireg[k] = Ik[wb + k];
  }
  __syncthreads();

  const int rowb = dl * 4096;  // byte base of this lane's row
  for (int lt = 0; lt < 8; ++lt) {
    const int lbase = lt * 256 + lg * 8;
    float acc[8] = {0.f, 0.f, 0.f, 0.f, 0.f, 0.f, 0.f, 0.f};
    for (int k = 0; k < KTOP; ++k) {
      const float w = wreg[k];
      const int p = (lbase + ireg[k]) & (Lz - 1);
      const int b0 = p >> 3;
      const int b1 = (b0 + 1) & 255;
      union { ushort8x v; unsigned d[4]; } A0, A1;
      A0.v = *(const ushort8x*)(lsb + GSWZ(rowb + 16 * b0));
      A1.v = *(const ushort8x*)(lsb + GSWZ(rowb + 16 * b1));
      const int h = p & 7;
      unsigned e0, e1, e2, e3, e4, e5;
      if (h & 4) { e0 = A0.d[2]; e1 = A0.d[3]; e2 = A1.d[0]; e3 = A1.d[1]; e4 = A1.d[2]; e5 = A1.d[3]; }
      else       { e0 = A0.d[0]; e1 = A0.d[1]; e2 = A0.d[2]; e3 = A0.d[3]; e4 = A1.d[0]; e5 = A1.d[1]; }
      unsigned f0, f1, f2, f3, f4;
      if (h & 2) { f0 = e1; f1 = e2; f2 = e3; f3 = e4; f4 = e5; }
      else       { f0 = e0; f1 = e1; f2 = e2; f3 = e3; f4 = e4; }
      const int sh = (h & 1) << 4;
      unsigned o0 = __builtin_amdgcn_alignbit(f1, f0, sh);
      unsigned o1 = __builtin_amdgcn_alignbit(f2, f1, sh);
      unsigned o2 = __builtin_amdgcn_alignbit(f3, f2, sh);
      unsigned o3 = __builtin_amdgcn_alignbit(f4, f3, sh);
      union { unsigned u; _Float16 hh[2]; } c0, c1, c2, c3;
      c0.u = o0; c1.u = o1; c2.u = o2; c3.u = o3;
      acc[0] += w * (float)c0.hh[0]; acc[1] += w * (float)c0.hh[1];
      acc[2] += w * (float)c1.hh[0]; acc[3] += w * (float)c1.hh[1];
      acc[4] += w * (float)c2.hh[0]; acc[5] += w * (float)c2.hh[1];
      acc[6] += w * (float)c3.hh[0]; acc[7] += w * (float)c3.hh[1];
    }
    __syncthreads();  // previous tile's os reads complete
    #pragma unroll
    for (int j = 0; j < 8; ++j) os[(lg * 8 + j) * 9 + dl] = acc[j];
    __syncthreads();
    #pragma unroll
    for (int c2 = 0; c2 < 2; ++c2) {
      const int sl = tid + 256 * c2;  // 512 slots
      const int l = sl >> 1, c = sl & 1;
      float4 o;
      o.x = os[l * 9 + 4 * c + 0];
      o.y = os[l * 9 + 4 * c + 1];
      o.z = os[l * 9 + 4 * c + 2];
      o.w = os[l * 9 + 4 * c + 3];
      *(float4*)&ob[(size_t)(lt * 256 + l) * Dz + d0 + 4 * c] = o;
    }
  }
}

// ---------------------------------------------------------------------------
extern "C" void kernel_launch(void* const* d_in, const int* in_sizes, int n_in,
                              void* d_out, int out_size, void* d_ws, size_t ws_size,
                              hipStream_t stream) {
  const float* Q = (const float*)d_in[0];
  const float* K = (const float*)d_in[1];
  const float* V = (const float*)d_in[2];
  const float* WQw = (const float*)d_in[3];
  const float* WQb = (const float*)d_in[4];
  const float* WKw = (const float*)d_in[5];
  const float* WKb = (const float*)d_in[6];
  const float* WVw = (const float*)d_in[7];
  const float* WVb = (const float*)d_in[8];
  float* out = (float*)d_out;

  const size_t CH = (size_t)Bz * Dz;        // 4096
  const size_t NEL = (size_t)Bz * Lz * Dz;  // 8388608

  char* ws = (char*)d_ws;
  _Float16* qT = (_Float16*)ws;                      // NEL fp16 (B,D,L)
  _Float16* kT = qT + NEL;                           // NEL fp16
  _Float16* vT = kT + NEL;                           // NEL fp16 (B,D,L)
  _Float16* WQt = vT + NEL;                          // 512x512 fp16 each
  _Float16* WKt = WQt + (size_t)Dz * Dz;
  _Float16* WVt = WKt + (size_t)Dz * Dz;
  float* Wk = (float*)(WVt + (size_t)Dz * Dz);
  int* Ik = (int*)(Wk + CH * KTOP);

  dim3 tr_block(32, 8);

  // weights -> fp16 transposed (N x K)
  wtrans3<<<dim3(16, 16, 3), tr_block, 0, stream>>>(WQw, WKw, WVw, WQt, WKt, WVt);

  // q, k, v -> fp16 transposed (B,D,L), single merged launch
  gemm3<<<dim3(Dz / 128, (Bz * Lz) / 128, 3), dim3(256), 0, stream>>>(
      Q, K, V, WQt, WKt, WVt, WQb, WKb, WVb, qT, kT, vT);

  // correlation (MFMA) + top-k + softmax per channel
  corr_mfma_topk<<<dim3((unsigned)CH), dim3(256), 0, stream>>>(qT, kT, Wk, Ik);

  // fused gather -> out (B,L,D)
  gather_fused<<<dim3(Dz / 8, Bz), dim3(256), 0, stream>>>(vT, Wk, Ik, out);
}

// Round 5
// 268.231 us; speedup vs baseline: 1.0150x; 1.0144x over previous
//
#include <hip/hip_runtime.h>
#include <hip/hip_bf16.h>
#include <math.h>

// Problem constants
#define Bz 8
#define Lz 2048
#define Dz 512
#define KTOP 15

typedef __attribute__((ext_vector_type(8))) unsigned short ushort8x;
typedef __attribute__((ext_vector_type(8))) _Float16 half8x;   // fp16x8 MFMA frag
typedef __attribute__((ext_vector_type(4))) float floatx4;     // fp32x4 MFMA acc
typedef __attribute__((ext_vector_type(16))) float float16x;   // fp32x16 MFMA acc (32x32)

// ---------------------------------------------------------------------------
// Transpose-cast the 3 weight matrices (K x N fp32) -> (N x K fp16)
// grid (16,16,3), block (32,8)
// ---------------------------------------------------------------------------
__global__ __launch_bounds__(256) void wtrans3(
    const float* __restrict__ w0, const float* __restrict__ w1,
    const float* __restrict__ w2, _Float16* __restrict__ t0,
    _Float16* __restrict__ t1, _Float16* __restrict__ t2) {
  const float* w = blockIdx.z == 0 ? w0 : (blockIdx.z == 1 ? w1 : w2);
  _Float16* t = blockIdx.z == 0 ? t0 : (blockIdx.z == 1 ? t1 : t2);
  __shared__ float tile[32][33];
  const int n0 = blockIdx.x * 32, k0 = blockIdx.y * 32;
  const int tx = threadIdx.x, ty = threadIdx.y;
  #pragma unroll
  for (int i = 0; i < 4; ++i)
    tile[ty + 8 * i][tx] = w[(size_t)(k0 + ty + 8 * i) * Dz + n0 + tx];
  __syncthreads();
  #pragma unroll
  for (int i = 0; i < 4; ++i)
    t[(size_t)(n0 + ty + 8 * i) * Dz + k0 + tx] = (_Float16)tile[tx][ty + 8 * i];
}

// ---------------------------------------------------------------------------
// Fused MFMA GEMM x3, A-fetch-minimal form: each block owns one 64-row
// A-panel and computes the FULL N=512 for it -> A (fp32, 96 MB total) is
// fetched from HBM exactly once. grid (256, 3): x = m-panel, y = operand.
// C[m,n] = sum_k A[m,k]*Bt[n,k] + bias[n], written fp16 TRANSPOSED per batch
// -> outT[(b*N + n)*2048 + l].
// A: 64 x K fp32 -> fp16 reg->LDS staging (padded rows, ALDA=40).
// B: full 512 x BK=32 fp16 slab per K-step via global_load_lds width-16 into
//    LINEAR LDS; bank spread via source pre-swizzle qs=q^(row&3) and the
//    matching XOR on the read side (both-sides involution).
// 4 waves, wave w = n-columns [128w,128w+128); 4x8 frags of 16x16x32 each,
// acc = 128 VGPR/thread; double-buffered LDS (75.8 KB), 2 blocks/CU.
// Epilogue: LDS retranspose TB[512][72-stride] -> 16B coalesced stores.
// ---------------------------------------------------------------------------
#define ALDA 40  // padded LDS row stride for A (fp16 elems); 80B rows
__global__ __launch_bounds__(256, 2) void gemm3(
    const float* __restrict__ A0, const float* __restrict__ A1,
    const float* __restrict__ A2, const _Float16* __restrict__ B0,
    const _Float16* __restrict__ B1, const _Float16* __restrict__ B2,
    const float* __restrict__ c0, const float* __restrict__ c1,
    const float* __restrict__ c2, _Float16* __restrict__ o0,
    _Float16* __restrict__ o1, _Float16* __restrict__ o2) {
  const int K = Dz;
  const int z = blockIdx.y;
  const float* A = z == 0 ? A0 : (z == 1 ? A1 : A2);
  const _Float16* Bt = z == 0 ? B0 : (z == 1 ? B1 : B2);
  const float* bias = z == 0 ? c0 : (z == 1 ? c1 : c2);
  _Float16* oT = z == 0 ? o0 : (z == 1 ? o1 : o2);

  __shared__ __attribute__((aligned(16))) _Float16 smem[37888];  // 75776 B
  _Float16* Asb = smem;           // [2][64*40]  = 2*2560
  _Float16* Bsb = smem + 5120;    // [2][512*32] = 2*16384, linear
  const int tid = threadIdx.x;
  const int m0 = blockIdx.x * 64;       // global m-panel
  const int lane = tid & 63;
  const int wv = tid >> 6;              // wave -> n-quarter
  const int ln = lane & 15;
  const int quad = lane >> 4;

  floatx4 acc[4][8];
  #pragma unroll
  for (int i = 0; i < 4; ++i)
    #pragma unroll
    for (int j = 0; j < 8; ++j) acc[i][j] = (floatx4){0.f, 0.f, 0.f, 0.f};

  float4 ra4[2];

  // ---- prologue: k-tile 0 ----
  #pragma unroll
  for (int j = 0; j < 2; ++j) {
    const int slot = tid + 256 * j;        // 512 slots
    const int r = slot >> 3, c4 = slot & 7;
    ra4[j] = *(const float4*)&A[(size_t)(m0 + r) * K + 4 * c4];
  }
  #pragma unroll
  for (int jj = 0; jj < 8; ++jj) {
    const int g = jj * 256 + tid;          // 2048 granules
    const int row = g >> 2;
    const int qs = (g & 3) ^ (row & 3);
    const unsigned short* src =
        (const unsigned short*)Bt + (size_t)row * K + 8 * qs;
    __builtin_amdgcn_global_load_lds(
        (const __attribute__((address_space(1))) unsigned int*)src,
        (__attribute__((address_space(3))) unsigned int*)
            &Bsb[(jj * 256 + wv * 64) * 8],
        16, 0, 0);
  }
  #pragma unroll
  for (int j = 0; j < 2; ++j) {
    const int slot = tid + 256 * j;
    const int r = slot >> 3, c4 = slot & 7;
    union { _Float16 h[4]; unsigned long long u; } p;
    p.h[0] = (_Float16)ra4[j].x;
    p.h[1] = (_Float16)ra4[j].y;
    p.h[2] = (_Float16)ra4[j].z;
    p.h[3] = (_Float16)ra4[j].w;
    *(unsigned long long*)&Asb[r * ALDA + 4 * c4] = p.u;
  }
  __syncthreads();

  const int NKT = K / 32;  // 16
  for (int kt = 0; kt < NKT; ++kt) {
    const int cur = kt & 1;
    const int nxt = cur ^ 1;
    if (kt + 1 < NKT) {
      const int kof = (kt + 1) * 32;
      #pragma unroll
      for (int j = 0; j < 2; ++j) {
        const int slot = tid + 256 * j;
        const int r = slot >> 3, c4 = slot & 7;
        ra4[j] = *(const float4*)&A[(size_t)(m0 + r) * K + kof + 4 * c4];
      }
      #pragma unroll
      for (int jj = 0; jj < 8; ++jj) {
        const int g = jj * 256 + tid;
        const int row = g >> 2;
        const int qs = (g & 3) ^ (row & 3);
        const unsigned short* src =
            (const unsigned short*)Bt + (size_t)row * K + kof + 8 * qs;
        __builtin_amdgcn_global_load_lds(
            (const __attribute__((address_space(1))) unsigned int*)src,
            (__attribute__((address_space(3))) unsigned int*)
                &Bsb[nxt * 16384 + (jj * 256 + wv * 64) * 8],
            16, 0, 0);
      }
    }
    const _Float16* As = Asb + cur * 2560;
    const _Float16* Bs = Bsb + cur * 16384;
    half8x af[4];
    #pragma unroll
    for (int i = 0; i < 4; ++i)
      af[i] = *(const half8x*)&As[(16 * i + ln) * ALDA + 8 * quad];
    #pragma unroll
    for (int j = 0; j < 8; ++j) {
      const int row = wv * 128 + 16 * j + ln;
      half8x bf = *(const half8x*)&Bs[row * 32 + 8 * (quad ^ (ln & 3))];
      #pragma unroll
      for (int i = 0; i < 4; ++i)
        acc[i][j] = __builtin_amdgcn_mfma_f32_16x16x32_f16(af[i], bf, acc[i][j], 0, 0, 0);
    }
    if (kt + 1 < NKT) {
      _Float16* Asw = Asb + nxt * 2560;
      #pragma unroll
      for (int j = 0; j < 2; ++j) {
        const int slot = tid + 256 * j;
        const int r = slot >> 3, c4 = slot & 7;
        union { _Float16 h[4]; unsigned long long u; } p;
        p.h[0] = (_Float16)ra4[j].x;
        p.h[1] = (_Float16)ra4[j].y;
        p.h[2] = (_Float16)ra4[j].z;
        p.h[3] = (_Float16)ra4[j].w;
        *(unsigned long long*)&Asw[r * ALDA + 4 * c4] = p.u;
      }
      __syncthreads();
    }
  }

  // ---- epilogue: retranspose via LDS (TB stride 72 halves = 144 B) ----
  __syncthreads();                 // all frag reads + B DMA drained
  _Float16* TB = smem;             // [512][72] = 73728 B <= 75776
  #pragma unroll
  for (int j = 0; j < 8; ++j) {
    const int n_l = wv * 128 + 16 * j + ln;
    const float bv = bias[n_l];
    #pragma unroll
    for (int i = 0; i < 4; ++i) {
      union { _Float16 h[4]; unsigned long long u; } p;
      #pragma unroll
      for (int r = 0; r < 4; ++r) p.h[r] = (_Float16)(acc[i][j][r] + bv);
      *(unsigned long long*)&TB[n_l * 72 + 16 * i + 4 * quad] = p.u;
    }
  }
  __syncthreads();
  const int bb = m0 >> 11;
  const int l0 = m0 & 2047;
  #pragma unroll
  for (int it = 0; it < 16; ++it) {
    const int slot = tid + 256 * it;   // 4096 slots of 16B
    const int d = slot >> 3, c = slot & 7;
    *(ushort8x*)(oT + ((size_t)(bb * Dz + d)) * Lz + l0 + 8 * c) =
        *(const ushort8x*)&TB[d * 72 + 8 * c];
  }
}

// ---------------------------------------------------------------------------
// Per-channel circular correlation via fp16 32x32x16 MFMA + ballot top-15.
// One block (256 threads, 4 waves) per (b,d) channel.  (unchanged)
// ---------------------------------------------------------------------------
#define QXS 2072  // halves per shifted copy; 4144 B = 259 x 16B slots (259 odd)

__device__ __forceinline__ int swz128(int byte) {
  return byte ^ (((byte >> 7) & 7) << 4);
}

__global__ __launch_bounds__(256) void corr_mfma_topk(
    const _Float16* __restrict__ qT, const _Float16* __restrict__ kT,
    float* __restrict__ Wk, int* __restrict__ Ik) {
  __shared__ __attribute__((aligned(16))) unsigned short qx[8 * QXS];
  __shared__ __attribute__((aligned(16))) unsigned short ke[Lz];
  __shared__ float cv[64];
  __shared__ int ci[64];

  const int tid = threadIdx.x;
  const size_t chan = (size_t)blockIdx.x * Lz;
  const unsigned short* qg = (const unsigned short*)(qT + chan);
  const unsigned short* kg = (const unsigned short*)(kT + chan);

  {
    ushort8x v = *(const ushort8x*)(kg + 8 * tid);
    *(ushort8x*)((char*)ke + swz128(16 * tid)) = v;
  }
  for (int c = tid; c < QXS / 8; c += 256) {  // 259 slots
    union { unsigned int d[8]; ushort8x v[2]; } b;
    b.v[0] = *(const ushort8x*)(qg + ((8 * c) & (Lz - 1)));
    b.v[1] = *(const ushort8x*)(qg + ((8 * c + 8) & (Lz - 1)));
    #pragma unroll
    for (int s = 0; s < 8; ++s) {
      union { unsigned int d[4]; ushort8x v; } w;
      if (s & 1) {
        #pragma unroll
        for (int t = 0; t < 4; ++t)
          w.d[t] = __builtin_amdgcn_alignbit(b.d[(s >> 1) + t + 1],
                                             b.d[(s >> 1) + t], 16);
      } else {
        #pragma unroll
        for (int t = 0; t < 4; ++t) w.d[t] = b.d[(s >> 1) + t];
      }
      *(ushort8x*)&qx[s * QXS + 8 * c] = w.v;
    }
  }
  __syncthreads();

  const int lane = tid & 63;
  const int wv = tid >> 6;
  const int jb = lane & 31;
  const int hi = lane >> 5;
  const char* aptr = (const char*)qx + (jb & 7) * (2 * QXS) + 16 * (jb >> 3) + 16 * hi;
  const int bb2 = ((8 * hi - 32 * jb) & (Lz - 1)) * 2;

  float16x acc0 = {0.f, 0.f, 0.f, 0.f, 0.f, 0.f, 0.f, 0.f,
                   0.f, 0.f, 0.f, 0.f, 0.f, 0.f, 0.f, 0.f};
  float16x acc1 = acc0;

  const int t0base = wv << 9;
  #pragma unroll 4
  for (int it = 0; it < 32; ++it) {
    const int t2 = 2 * (t0base + 16 * it);
    half8x a = *(const half8x*)(aptr + t2);
    const int y0 = (bb2 + t2) & (2 * Lz - 1);
    const int y1 = (y0 + 2048) & (2 * Lz - 1);
    half8x b0 = *(const half8x*)((const char*)ke + swz128(y0));
    half8x b1 = *(const half8x*)((const char*)ke + swz128(y1));
    acc0 = __builtin_amdgcn_mfma_f32_32x32x16_f16(a, b0, acc0, 0, 0, 0);
    acc1 = __builtin_amdgcn_mfma_f32_32x32x16_f16(a, b1, acc1, 0, 0, 0);
  }

  __syncthreads();
  float* red = (float*)qx;
  {
    const int rbase = wv * 8192;
    #pragma unroll
    for (int g = 0; g < 4; ++g) {
      const int tau0 = 8 * g + 4 * hi + 32 * jb;
      float4 p0, p1;
      p0.x = acc0[4 * g + 0]; p0.y = acc0[4 * g + 1];
      p0.z = acc0[4 * g + 2]; p0.w = acc0[4 * g + 3];
      p1.x = acc1[4 * g + 0]; p1.y = acc1[4 * g + 1];
      p1.z = acc1[4 * g + 2]; p1.w = acc1[4 * g + 3];
      *(float4*)((char*)red + swz128(rbase + 4 * tau0)) = p0;
      *(float4*)((char*)red + swz128(rbase + 4 * (tau0 + 1024))) = p1;
    }
  }
  __syncthreads();

  float vals[8] = {0.f, 0.f, 0.f, 0.f, 0.f, 0.f, 0.f, 0.f};
  {
    const char* rb = (const char*)red;
    #pragma unroll
    for (int w = 0; w < 4; ++w) {
      float4 a0 = *(const float4*)(rb + swz128(w * 8192 + 32 * tid));
      float4 a1 = *(const float4*)(rb + swz128(w * 8192 + 32 * tid + 16));
      vals[0] += a0.x; vals[1] += a0.y; vals[2] += a0.z; vals[3] += a0.w;
      vals[4] += a1.x; vals[5] += a1.y; vals[6] += a1.z; vals[7] += a1.w;
    }
  }

  unsigned key[8];
  #pragma unroll
  for (int j = 0; j < 8; ++j) {
    const unsigned u = __float_as_uint(vals[j]);
    key[j] = u ^ (unsigned)(((int)u >> 31) | 0x80000000);
  }
  unsigned p = 0;
  for (int b = 31; b >= 0; --b) {
    const unsigned c = p | (1u << b);
    int cnt = 0;
    #pragma unroll
    for (int j = 0; j < 8; ++j)
      cnt += __popcll(__ballot(key[j] >= c));
    if (cnt >= KTOP) p = c;
  }
  const unsigned long long ltm = (1ull << lane) - 1ull;
  int base = 0;
  #pragma unroll
  for (int j = 0; j < 8; ++j) {
    const bool g = key[j] > p;
    const unsigned long long m = __ballot(g);
    const int pos = base + __popcll(m & ltm);
    if (g) { cv[wv * KTOP + pos] = vals[j]; ci[wv * KTOP + pos] = 8 * tid + j; }
    base += __popcll(m);
  }
  #pragma unroll
  for (int j = 0; j < 8; ++j) {
    const bool e = (key[j] == p);
    const unsigned long long m = __ballot(e);
    const int pos = base + __popcll(m & ltm);
    if (e && pos < KTOP) { cv[wv * KTOP + pos] = vals[j]; ci[wv * KTOP + pos] = 8 * tid + j; }
    base += __popcll(m);
  }
  __syncthreads();

  if (wv == 0) {
    const bool act = lane < 4 * KTOP;
    const float v = act ? cv[lane] : 0.f;
    const int ti = act ? ci[lane] : 0;
    unsigned k2 = 0;
    if (act) {
      const unsigned u = __float_as_uint(v);
      k2 = u ^ (unsigned)(((int)u >> 31) | 0x80000000);
    }
    unsigned pp = 0;
    for (int b = 31; b >= 0; --b) {
      const unsigned c = pp | (1u << b);
      if (__popcll(__ballot(k2 >= c)) >= KTOP) pp = c;
    }
    const unsigned long long mg = __ballot(k2 > pp);
    const int tot = __popcll(mg);
    bool sel = (k2 > pp);
    int pos = __popcll(mg & ltm);
    const unsigned long long me = __ballot(k2 == pp);
    const int pose = tot + __popcll(me & ltm);
    if (k2 == pp && pose < KTOP) { sel = true; pos = pose; }
    if (sel) { cv[pos] = v; ci[pos] = ti; }
    const float sv = (lane < KTOP) ? cv[lane] : -3.0e38f;
    const int si = (lane < KTOP) ? ci[lane] : 0;
    float gm = sv;
    #pragma unroll
    for (int off = 1; off < 64; off <<= 1)
      gm = fmaxf(gm, __shfl_xor(gm, off, 64));
    float e = (lane < KTOP) ? expf(sv - gm) : 0.f;
    float es = e;
    #pragma unroll
    for (int off = 1; off < 64; off <<= 1) es += __shfl_xor(es, off, 64);
    if (lane < KTOP) {
      const size_t ob = (size_t)blockIdx.x * KTOP;
      Wk[ob + lane] = e / es;
      Ik[ob + lane] = si;
    }
  }
}

// ---------------------------------------------------------------------------
// Fused gather v2: out[b,l,d] = sum_k w[b,d,k] * vT[b,d,(l+I[b,d,k]) mod L]
// vT is fp16 (B,D,L). Block = 8 d-channels, 256 threads, grid (D/8, B).
// ---------------------------------------------------------------------------
#define GSWZ(b) ((b) ^ ((((b) >> 12) & 7) << 4))  // XOR slot bits 0..2 with dl

__global__ __launch_bounds__(256) void gather_fused(
    const _Float16* __restrict__ vT, const float* __restrict__ Wk,
    const int* __restrict__ Ik, float* __restrict__ out) {
  __shared__ __attribute__((aligned(16))) _Float16 ls[8 * Lz];  // 32 KB swizzled
  __shared__ float os[256 * 9];                                 // 9 KB out-staging
  const int tid = threadIdx.x;
  const int d0 = blockIdx.x * 8;
  const int b = blockIdx.y;
  float* ob = out + (size_t)b * Lz * Dz;

  // stage vT[b, d0..d0+8, :] -> ls (swizzled), 16B granules
  const char* lsb = (const char*)ls;
  #pragma unroll
  for (int it = 0; it < 8; ++it) {
    const int slot = tid + 256 * it;          // 2048 slots of 16B
    const int dl2 = slot >> 8, c = slot & 255;
    ushort8x v = *(const ushort8x*)((const unsigned short*)vT +
                                    ((size_t)(b * Dz + d0 + dl2) * Lz) + 8 * c);
    *(ushort8x*)((char*)ls + GSWZ(16 * slot)) = v;
  }

  const int dl = tid & 7;
  const int lg = tid >> 3;  // [0,32)
  const size_t wb = ((size_t)b * Dz + d0 + dl) * KTOP;
  float wreg[KTOP];
  int ireg[KTOP];
  #pragma unroll
  for (int k = 0; k < KTOP; ++k) {
    wreg[k] = Wk[wb + k];
    ireg[k] = Ik[wb + k];
  }
  __syncthreads();

  const int rowb = dl * 4096;  // byte base of this lane's row
  for (int lt = 0; lt < 8; ++lt) {
    const int lbase = lt * 256 + lg * 8;
    float acc[8] = {0.f, 0.f, 0.f, 0.f, 0.f, 0.f, 0.f, 0.f};
    for (int k = 0; k < KTOP; ++k) {
      const float w = wreg[k];
      const int p = (lbase + ireg[k]) & (Lz - 1);
      const int b0 = p >> 3;
      const int b1 = (b0 + 1) & 255;
      union { ushort8x v; unsigned d[4]; } A0, A1;
      A0.v = *(const ushort8x*)(lsb + GSWZ(rowb + 16 * b0));
      A1.v = *(const ushort8x*)(lsb + GSWZ(rowb + 16 * b1));
      const int h = p & 7;
      unsigned e0, e1, e2, e3, e4, e5;
      if (h & 4) { e0 = A0.d[2]; e1 = A0.d[3]; e2 = A1.d[0]; e3 = A1.d[1]; e4 = A1.d[2]; e5 = A1.d[3]; }
      else       { e0 = A0.d[0]; e1 = A0.d[1]; e2 = A0.d[2]; e3 = A0.d[3]; e4 = A1.d[0]; e5 = A1.d[1]; }
      unsigned f0, f1, f2, f3, f4;
      if (h & 2) { f0 = e1; f1 = e2; f2 = e3; f3 = e4; f4 = e5; }
      else       { f0 = e0; f1 = e1; f2 = e2; f3 = e3; f4 = e4; }
      const int sh = (h & 1) << 4;
      unsigned o0 = __builtin_amdgcn_alignbit(f1, f0, sh);
      unsigned o1 = __builtin_amdgcn_alignbit(f2, f1, sh);
      unsigned o2 = __builtin_amdgcn_alignbit(f3, f2, sh);
      unsigned o3 = __builtin_amdgcn_alignbit(f4, f3, sh);
      union { unsigned u; _Float16 hh[2]; } c0, c1, c2, c3;
      c0.u = o0; c1.u = o1; c2.u = o2; c3.u = o3;
      acc[0] += w * (float)c0.hh[0]; acc[1] += w * (float)c0.hh[1];
      acc[2] += w * (float)c1.hh[0]; acc[3] += w * (float)c1.hh[1];
      acc[4] += w * (float)c2.hh[0]; acc[5] += w * (float)c2.hh[1];
      acc[6] += w * (float)c3.hh[0]; acc[7] += w * (float)c3.hh[1];
    }
    __syncthreads();  // previous tile's os reads complete
    #pragma unroll
    for (int j = 0; j < 8; ++j) os[(lg * 8 + j) * 9 + dl] = acc[j];
    __syncthreads();
    #pragma unroll
    for (int c2 = 0; c2 < 2; ++c2) {
      const int sl = tid + 256 * c2;  // 512 slots
      const int l = sl >> 1, c = sl & 1;
      float4 o;
      o.x = os[l * 9 + 4 * c + 0];
      o.y = os[l * 9 + 4 * c + 1];
      o.z = os[l * 9 + 4 * c + 2];
      o.w = os[l * 9 + 4 * c + 3];
      *(float4*)&ob[(size_t)(lt * 256 + l) * Dz + d0 + 4 * c] = o;
    }
  }
}

// ---------------------------------------------------------------------------
extern "C" void kernel_launch(void* const* d_in, const int* in_sizes, int n_in,
                              void* d_out, int out_size, void* d_ws, size_t ws_size,
                              hipStream_t stream) {
  const float* Q = (const float*)d_in[0];
  const float* K = (const float*)d_in[1];
  const float* V = (const float*)d_in[2];
  const float* WQw = (const float*)d_in[3];
  const float* WQb = (const float*)d_in[4];
  const float* WKw = (const float*)d_in[5];
  const float* WKb = (const float*)d_in[6];
  const float* WVw = (const float*)d_in[7];
  const float* WVb = (const float*)d_in[8];
  float* out = (float*)d_out;

  const size_t CH = (size_t)Bz * Dz;        // 4096
  const size_t NEL = (size_t)Bz * Lz * Dz;  // 8388608

  char* ws = (char*)d_ws;
  _Float16* qT = (_Float16*)ws;                      // NEL fp16 (B,D,L)
  _Float16* kT = qT + NEL;                           // NEL fp16
  _Float16* vT = kT + NEL;                           // NEL fp16 (B,D,L)
  _Float16* WQt = vT + NEL;                          // 512x512 fp16 each
  _Float16* WKt = WQt + (size_t)Dz * Dz;
  _Float16* WVt = WKt + (size_t)Dz * Dz;
  float* Wk = (float*)(WVt + (size_t)Dz * Dz);
  int* Ik = (int*)(Wk + CH * KTOP);

  dim3 tr_block(32, 8);

  // weights -> fp16 transposed (N x K)
  wtrans3<<<dim3(16, 16, 3), tr_block, 0, stream>>>(WQw, WKw, WVw, WQt, WKt, WVt);

  // q, k, v -> fp16 transposed (B,D,L); A-fetch-minimal 64x512 blocks
  gemm3<<<dim3((Bz * Lz) / 64, 3), dim3(256), 0, stream>>>(
      Q, K, V, WQt, WKt, WVt, WQb, WKb, WVb, qT, kT, vT);

  // correlation (MFMA) + top-k + softmax per channel
  corr_mfma_topk<<<dim3((unsigned)CH), dim3(256), 0, stream>>>(qT, kT, Wk, Ik);

  // fused gather -> out (B,L,D)
  gather_fused<<<dim3(Dz / 8, Bz), dim3(256), 0, stream>>>(vT, Wk, Ik, out);
}